// Round 7
// baseline (108.842 us; speedup 1.0000x reference)
//
#include <hip/hip_runtime.h>

#define N_NODES 20000
#define N_EDGES 640000
#define HIDDEN  64
#define BATCH   8
#define NB_SCAN ((N_NODES + 255) / 256)   // 79 blocks
#define NORM_SCALE 131071.0f              // 2^17 - 1
#define NORM_INV   7.62945274e-6f         // 1 / 131071

typedef unsigned long long ull;

__device__ inline int wave_iscan(int v, int lane) {
#pragma unroll
    for (int off = 1; off < 64; off <<= 1) {
        int u = __shfl_up(v, off, 64);
        if (lane >= off) v += u;
    }
    return v;
}

// ---- 0. zero the histogram accumulator ----
__global__ void k_zero(ull* __restrict__ packed, int N) {
    int i = blockIdx.x * blockDim.x + threadIdx.x;
    if (i < N) packed[i] = 0ULL;
}

// ---- 1. histogram: packed[col] += (1<<40) | fx(ew)  (count | fixed-point deg) ----
__global__ void k_hist(const int* __restrict__ col, const float* __restrict__ ew,
                       ull* __restrict__ packed, int E) {
    int e = blockIdx.x * blockDim.x + threadIdx.x;
    if (e >= E) return;
    int c = col[e];
    ull fx = (ull)(ew[e] * 16777216.0f + 0.5f); // 2^24 fixed point
    atomicAdd(&packed[c], (1ULL << 40) | fx);
}

// ---- 2a. per-block exclusive scan of counts; dis = rsqrt(deg+1); fused x->xT transpose ----
__global__ void k_scan1(const ull* __restrict__ packed,
                        int* __restrict__ pre, int* __restrict__ bsum,
                        float* __restrict__ dis,
                        const float* __restrict__ x, float* __restrict__ xT, int N) {
    int tid = threadIdx.x;
    int i = blockIdx.x * 256 + tid;
    int lane = tid & 63, wid = tid >> 6;
    ull p = (i < N) ? packed[i] : 0ULL;
    int v = (int)(p >> 40);
    if (i < N) {
        float deg = (float)(p & 0xFFFFFFFFFFULL) * 5.9604644775390625e-8f; // 2^-24
        dis[i] = rsqrtf(deg + 1.0f);
        float4 lo, hi;
        lo.x = x[0 * N + i]; lo.y = x[1 * N + i]; lo.z = x[2 * N + i]; lo.w = x[3 * N + i];
        hi.x = x[4 * N + i]; hi.y = x[5 * N + i]; hi.z = x[6 * N + i]; hi.w = x[7 * N + i];
        ((float4*)xT)[i * 2]     = lo;
        ((float4*)xT)[i * 2 + 1] = hi;
    }
    int incl = wave_iscan(v, lane);
    __shared__ int ws[4];
    if (lane == 63) ws[wid] = incl;
    __syncthreads();
    if (tid == 0) {
        int r = 0;
#pragma unroll
        for (int w = 0; w < 4; ++w) { int s = ws[w]; ws[w] = r; r += s; }
    }
    __syncthreads();
    int excl = incl - v + ws[wid];
    if (i < N) pre[i] = excl;
    if (tid == 255) bsum[blockIdx.x] = excl + v;   // block total
}

// ---- 2b. add block offsets (each block sums its own bsum prefix) -> starts, cursor ----
__global__ void k_scan3(const int* __restrict__ pre, const int* __restrict__ bsum,
                        int* __restrict__ starts, int* __restrict__ cursor, int N) {
    __shared__ int offs;
    int tid = threadIdx.x;
    if (tid < 64) {
        int v = 0;
        if (tid < blockIdx.x) v = bsum[tid];
        int t2 = tid + 64;
        if (t2 < blockIdx.x) v += bsum[t2];
#pragma unroll
        for (int m = 1; m < 64; m <<= 1) v += __shfl_xor(v, m, 64);
        if (tid == 0) offs = v;
    }
    __syncthreads();
    int i = blockIdx.x * 256 + tid;
    if (i < N) { int s = pre[i] + offs; starts[i] = s; cursor[i] = s; }
    if (blockIdx.x == 0 && tid == 0) starts[N_NODES] = N_EDGES;
}

// ---- 3. scatter edges into CSR buckets as 4B records: (row << 17) | q17(norm) ----
__global__ void k_scatter(const int* __restrict__ row, const int* __restrict__ col,
                          const float* __restrict__ ew, const float* __restrict__ dis,
                          int* __restrict__ cursor, unsigned* __restrict__ sedge, int E) {
    int e = blockIdx.x * blockDim.x + threadIdx.x;
    if (e >= E) return;
    int r = row[e], c = col[e];
    float nr = dis[r] * ew[e] * dis[c];          // in [0, 1]
    unsigned q = (unsigned)(nr * NORM_SCALE + 0.5f);
    if (q > 131071u) q = 131071u;
    int pos = atomicAdd(&cursor[c], 1);
    sedge[pos] = ((unsigned)r << 17) | q;
}

// ---- 4. gather pass 1 (split-K=4) + distributed MLP fold -> t ----
// thread i: node n = i>>5, chunk k = (i>>3)&3, batch b = i&7
__global__ void k_gather1(const int* __restrict__ starts, const unsigned* __restrict__ sedge,
                          const float* __restrict__ xT, const float* __restrict__ dis,
                          const float* __restrict__ W1, const float* __restrict__ b1,
                          const float* __restrict__ W2, const float* __restrict__ b2,
                          float* __restrict__ t, int N) {
    int i = blockIdx.x * blockDim.x + threadIdx.x;
    if (i >= N * 32) return;
    int n = i >> 5;
    int w = i & 31, k = w >> 3, b = w & 7;
    int e0 = starts[n], e1 = starts[n + 1], len = e1 - e0;
    int j0 = e0 + ((len * k) >> 2);
    int j1 = e0 + ((len * (k + 1)) >> 2);
    float s = 0.0f;
    for (int j = j0; j < j1; ++j) {
        unsigned v = sedge[j];
        float nr = (float)(v & 0x1FFFFu) * NORM_INV;
        s = fmaf(nr, xT[(int)((v >> 17) << 3) + b], s);
    }
    // combine the 4 chunks (lanes xor 8, 16 stay within the 32-lane node group)
    s += __shfl_xor(s, 8, 64);
    s += __shfl_xor(s, 16, 64);
    float di = dis[n];
    s = fmaf(di * di, xT[(n << 3) + b], s);     // self-loop (all copies identical)
    // distributed MLP: each k-lane folds 16 hidden units, then combine
    float acc = 0.0f;
#pragma unroll
    for (int ff = 0; ff < 16; ++ff) {
        int f = (k << 4) + ff;
        float h = fmaf(s, W1[f], b1[f]);
        acc = fmaf(fmaxf(h, 0.0f), W2[f], acc);
    }
    acc += __shfl_xor(acc, 8, 64);
    acc += __shfl_xor(acc, 16, 64);
    if (k == 0) t[(n << 3) + b] = acc;
}

// ---- 5. gather pass 2 (split-K=4) + fused epilogue -> out [B][N] ----
__global__ void k_gather2(const int* __restrict__ starts, const unsigned* __restrict__ sedge,
                          const float* __restrict__ t, const float* __restrict__ xT,
                          const float* __restrict__ dis, const float* __restrict__ b2,
                          float* __restrict__ out, int N) {
    int i = blockIdx.x * blockDim.x + threadIdx.x;
    if (i >= N * 32) return;
    int n = i >> 5;
    int w = i & 31, k = w >> 3, b = w & 7;
    int e0 = starts[n], e1 = starts[n + 1], len = e1 - e0;
    int j0 = e0 + ((len * k) >> 2);
    int j1 = e0 + ((len * (k + 1)) >> 2);
    float g = 0.0f;
    for (int j = j0; j < j1; ++j) {
        unsigned v = sedge[j];
        float nr = (float)(v & 0x1FFFFu) * NORM_INV;
        g = fmaf(nr, t[(int)((v >> 17) << 3) + b], g);
    }
    g += __shfl_xor(g, 8, 64);
    g += __shfl_xor(g, 16, 64);
    if (k == 0) {
        float di = dis[n];
        g = fmaf(di * di, t[(n << 3) + b], g);   // self-loop
        out[b * N + n] = xT[(n << 3) + b] + 0.5f * (b2[0] + g);
    }
}

// ---------------- launch ----------------
extern "C" void kernel_launch(void* const* d_in, const int* in_sizes, int n_in,
                              void* d_out, int out_size, void* d_ws, size_t ws_size,
                              hipStream_t stream) {
    const float* x  = (const float*)d_in[0];
    const int*   ei = (const int*)d_in[1];      // [2, E] int32
    const float* ew = (const float*)d_in[2];
    const float* W1 = (const float*)d_in[3];
    const float* b1 = (const float*)d_in[4];
    const float* W2 = (const float*)d_in[5];
    const float* b2 = (const float*)d_in[6];
    float* out = (float*)d_out;

    const int N = N_NODES, E = N_EDGES;
    const int* row = ei;
    const int* col = ei + E;

    // workspace layout (8B-aligned chunks first)
    ull*      packed = (ull*)d_ws;               // N ull (zeroed by k_zero)
    unsigned* sedge  = (unsigned*)(packed + N);  // E u32
    float*    xT     = (float*)(sedge + E);      // N*BATCH (16B aligned)
    float*    t      = xT + N * BATCH;           // N*BATCH
    int*      pre    = (int*)(t + N * BATCH);    // N
    int*      bsum   = pre + N;                  // 128
    int*      starts = bsum + 128;               // N+1
    int*      cursor = starts + N + 1;           // N
    float*    dis    = (float*)(cursor + N);     // N

    const int BS = 256;
    int gE  = (E + BS - 1) / BS;
    int gS  = (N * 32 + BS - 1) / BS;            // 2500 blocks for split-K gathers

    k_zero   <<<NB_SCAN, 256, 0, stream>>>(packed, N);
    k_hist   <<<gE,      BS,  0, stream>>>(col, ew, packed, E);
    k_scan1  <<<NB_SCAN, 256, 0, stream>>>(packed, pre, bsum, dis, x, xT, N);
    k_scan3  <<<NB_SCAN, 256, 0, stream>>>(pre, bsum, starts, cursor, N);
    k_scatter<<<gE,      BS,  0, stream>>>(row, col, ew, dis, cursor, sedge, E);
    k_gather1<<<gS,      BS,  0, stream>>>(starts, sedge, xT, dis, W1, b1, W2, b2, t, N);
    k_gather2<<<gS,      BS,  0, stream>>>(starts, sedge, t, xT, dis, b2, out, N);
}

// Round 8
// 104.274 us; speedup vs baseline: 1.0438x; 1.0438x over previous
//
#include <hip/hip_runtime.h>

#define N_NODES 20000
#define N_EDGES 640000
#define HIDDEN  64
#define BATCH   8
#define NB_SCAN ((N_NODES + 255) / 256)   // 79 blocks

typedef unsigned long long ull;

__device__ inline int wave_iscan(int v, int lane) {
#pragma unroll
    for (int off = 1; off < 64; off <<= 1) {
        int u = __shfl_up(v, off, 64);
        if (lane >= off) v += u;
    }
    return v;
}

// ---- 0. zero the histogram accumulator ----
__global__ void k_zero(ull* __restrict__ packed, int N) {
    int i = blockIdx.x * blockDim.x + threadIdx.x;
    if (i < N) packed[i] = 0ULL;
}

// ---- 1. histogram: packed[col] += (1<<40) | fx(ew)  (count | fixed-point deg) ----
__global__ void k_hist(const int* __restrict__ col, const float* __restrict__ ew,
                       ull* __restrict__ packed, int E) {
    int e = blockIdx.x * blockDim.x + threadIdx.x;
    if (e >= E) return;
    int c = col[e];
    ull fx = (ull)(ew[e] * 16777216.0f + 0.5f); // 2^24 fixed point
    atomicAdd(&packed[c], (1ULL << 40) | fx);
}

// ---- 2a. per-block exclusive scan of counts; dis = rsqrt(deg+1); fused x->xT transpose ----
__global__ void k_scan1(const ull* __restrict__ packed,
                        int* __restrict__ pre, int* __restrict__ bsum,
                        float* __restrict__ dis,
                        const float* __restrict__ x, float* __restrict__ xT, int N) {
    int tid = threadIdx.x;
    int i = blockIdx.x * 256 + tid;
    int lane = tid & 63, wid = tid >> 6;
    ull p = (i < N) ? packed[i] : 0ULL;
    int v = (int)(p >> 40);
    if (i < N) {
        float deg = (float)(p & 0xFFFFFFFFFFULL) * 5.9604644775390625e-8f; // 2^-24
        dis[i] = rsqrtf(deg + 1.0f);
        float4 lo, hi;
        lo.x = x[0 * N + i]; lo.y = x[1 * N + i]; lo.z = x[2 * N + i]; lo.w = x[3 * N + i];
        hi.x = x[4 * N + i]; hi.y = x[5 * N + i]; hi.z = x[6 * N + i]; hi.w = x[7 * N + i];
        ((float4*)xT)[i * 2]     = lo;
        ((float4*)xT)[i * 2 + 1] = hi;
    }
    int incl = wave_iscan(v, lane);
    __shared__ int ws[4];
    if (lane == 63) ws[wid] = incl;
    __syncthreads();
    if (tid == 0) {
        int r = 0;
#pragma unroll
        for (int w = 0; w < 4; ++w) { int s = ws[w]; ws[w] = r; r += s; }
    }
    __syncthreads();
    int excl = incl - v + ws[wid];
    if (i < N) pre[i] = excl;
    if (tid == 255) bsum[blockIdx.x] = excl + v;   // block total
}

// ---- 2b. add block offsets (each block sums its own bsum prefix) -> starts, cursor ----
__global__ void k_scan3(const int* __restrict__ pre, const int* __restrict__ bsum,
                        int* __restrict__ starts, int* __restrict__ cursor, int N) {
    __shared__ int offs;
    int tid = threadIdx.x;
    if (tid < 64) {
        int v = 0;
        if (tid < blockIdx.x) v = bsum[tid];
        int t2 = tid + 64;
        if (t2 < blockIdx.x) v += bsum[t2];
#pragma unroll
        for (int m = 1; m < 64; m <<= 1) v += __shfl_xor(v, m, 64);
        if (tid == 0) offs = v;
    }
    __syncthreads();
    int i = blockIdx.x * 256 + tid;
    if (i < N) { int s = pre[i] + offs; starts[i] = s; cursor[i] = s; }
    if (blockIdx.x == 0 && tid == 0) starts[N_NODES] = N_EDGES;
}

// ---- 3. scatter, 4 edges/thread for memory-level parallelism ----
// 8B records: (row << 32) | f32 bits of norm
__global__ void k_scatter(const int* __restrict__ row, const int* __restrict__ col,
                          const float* __restrict__ ew, const float* __restrict__ dis,
                          int* __restrict__ cursor, ull* __restrict__ sedge, int E) {
    int base = (blockIdx.x * blockDim.x + threadIdx.x) * 4;
    if (base >= E) return;
    // coalesced 16B vector loads (E is divisible by 4; arrays 16B-aligned)
    int4   r4 = *(const int4*)  (row + base);
    int4   c4 = *(const int4*)  (col + base);
    float4 w4 = *(const float4*)(ew  + base);
    int r[4] = {r4.x, r4.y, r4.z, r4.w};
    int c[4] = {c4.x, c4.y, c4.z, c4.w};
    float w[4] = {w4.x, w4.y, w4.z, w4.w};
    // 4 independent atomics in flight
    int pos[4];
#pragma unroll
    for (int q = 0; q < 4; ++q) pos[q] = atomicAdd(&cursor[c[q]], 1);
    // 4 independent norm computations + scattered stores
#pragma unroll
    for (int q = 0; q < 4; ++q) {
        float nr = dis[r[q]] * w[q] * dis[c[q]];
        sedge[pos[q]] = ((ull)(unsigned)r[q] << 32) | (ull)__float_as_uint(nr);
    }
}

// ---- 4. gather pass 1 (split-K=4) + distributed MLP fold -> t ----
// thread i: node n = i>>5, chunk k = (i>>3)&3, batch b = i&7
__global__ void k_gather1(const int* __restrict__ starts, const ull* __restrict__ sedge,
                          const float* __restrict__ xT, const float* __restrict__ dis,
                          const float* __restrict__ W1, const float* __restrict__ b1,
                          const float* __restrict__ W2, const float* __restrict__ b2,
                          float* __restrict__ t, int N) {
    int i = blockIdx.x * blockDim.x + threadIdx.x;
    if (i >= N * 32) return;
    int n = i >> 5;
    int w = i & 31, k = w >> 3, b = w & 7;
    int e0 = starts[n], e1 = starts[n + 1], len = e1 - e0;
    int j0 = e0 + ((len * k) >> 2);
    int j1 = e0 + ((len * (k + 1)) >> 2);
    float s = 0.0f;
    for (int j = j0; j < j1; ++j) {
        ull v = sedge[j];
        s = fmaf(__uint_as_float((unsigned)v), xT[((int)(v >> 32) << 3) + b], s);
    }
    // combine the 4 chunks (lanes xor 8, 16 stay within the 32-lane node group)
    s += __shfl_xor(s, 8, 64);
    s += __shfl_xor(s, 16, 64);
    float di = dis[n];
    s = fmaf(di * di, xT[(n << 3) + b], s);     // self-loop (all copies identical)
    // distributed MLP: each k-lane folds 16 hidden units, then combine
    float acc = 0.0f;
#pragma unroll
    for (int ff = 0; ff < 16; ++ff) {
        int f = (k << 4) + ff;
        float h = fmaf(s, W1[f], b1[f]);
        acc = fmaf(fmaxf(h, 0.0f), W2[f], acc);
    }
    acc += __shfl_xor(acc, 8, 64);
    acc += __shfl_xor(acc, 16, 64);
    if (k == 0) t[(n << 3) + b] = acc;
}

// ---- 5. gather pass 2 (split-K=4) + fused epilogue -> out [B][N] ----
__global__ void k_gather2(const int* __restrict__ starts, const ull* __restrict__ sedge,
                          const float* __restrict__ t, const float* __restrict__ xT,
                          const float* __restrict__ dis, const float* __restrict__ b2,
                          float* __restrict__ out, int N) {
    int i = blockIdx.x * blockDim.x + threadIdx.x;
    if (i >= N * 32) return;
    int n = i >> 5;
    int w = i & 31, k = w >> 3, b = w & 7;
    int e0 = starts[n], e1 = starts[n + 1], len = e1 - e0;
    int j0 = e0 + ((len * k) >> 2);
    int j1 = e0 + ((len * (k + 1)) >> 2);
    float g = 0.0f;
    for (int j = j0; j < j1; ++j) {
        ull v = sedge[j];
        g = fmaf(__uint_as_float((unsigned)v), t[((int)(v >> 32) << 3) + b], g);
    }
    g += __shfl_xor(g, 8, 64);
    g += __shfl_xor(g, 16, 64);
    if (k == 0) {
        float di = dis[n];
        g = fmaf(di * di, t[(n << 3) + b], g);   // self-loop
        out[b * N + n] = xT[(n << 3) + b] + 0.5f * (b2[0] + g);
    }
}

// ---------------- launch ----------------
extern "C" void kernel_launch(void* const* d_in, const int* in_sizes, int n_in,
                              void* d_out, int out_size, void* d_ws, size_t ws_size,
                              hipStream_t stream) {
    const float* x  = (const float*)d_in[0];
    const int*   ei = (const int*)d_in[1];      // [2, E] int32
    const float* ew = (const float*)d_in[2];
    const float* W1 = (const float*)d_in[3];
    const float* b1 = (const float*)d_in[4];
    const float* W2 = (const float*)d_in[5];
    const float* b2 = (const float*)d_in[6];
    float* out = (float*)d_out;

    const int N = N_NODES, E = N_EDGES;
    const int* row = ei;
    const int* col = ei + E;

    // workspace layout (8B-aligned chunks first)
    ull*   packed = (ull*)d_ws;                  // N ull (zeroed by k_zero)
    ull*   sedge  = packed + N;                  // E ull
    float* xT     = (float*)(sedge + E);         // N*BATCH (16B aligned)
    float* t      = xT + N * BATCH;              // N*BATCH
    int*   pre    = (int*)(t + N * BATCH);       // N
    int*   bsum   = pre + N;                     // 128
    int*   starts = bsum + 128;                  // N+1
    int*   cursor = starts + N + 1;              // N
    float* dis    = (float*)(cursor + N);        // N

    const int BS = 256;
    int gE  = (E + BS - 1) / BS;
    int gE4 = (E / 4 + BS - 1) / BS;             // 625 blocks, 4 edges/thread
    int gS  = (N * 32 + BS - 1) / BS;            // 2500 blocks for split-K gathers

    k_zero   <<<NB_SCAN, 256, 0, stream>>>(packed, N);
    k_hist   <<<gE,      BS,  0, stream>>>(col, ew, packed, E);
    k_scan1  <<<NB_SCAN, 256, 0, stream>>>(packed, pre, bsum, dis, x, xT, N);
    k_scan3  <<<NB_SCAN, 256, 0, stream>>>(pre, bsum, starts, cursor, N);
    k_scatter<<<gE4,     BS,  0, stream>>>(row, col, ew, dis, cursor, sedge, E);
    k_gather1<<<gS,      BS,  0, stream>>>(starts, sedge, xT, dis, W1, b1, W2, b2, t, N);
    k_gather2<<<gS,      BS,  0, stream>>>(starts, sedge, t, xT, dis, b2, out, N);
}